// Round 43
// baseline (2229.321 us; speedup 1.0000x reference)
//
#include <hip/hip_runtime.h>
#include <cstdint>
#include <cmath>

__global__ __launch_bounds__(256) void k_count(const int* __restrict__ r,const int* __restrict__ c,
    int* __restrict__ cr,int* __restrict__ cc,int e){
  int i=blockIdx.x*256+threadIdx.x;
  if(i<e){atomicAdd(&cr[r[i]],1);atomicAdd(&cc[c[i]],1);}
}

__global__ __launch_bounds__(1024) void k_scan(const int* __restrict__ cr,const int* __restrict__ cc,
    int* __restrict__ sr,int* __restrict__ sc,int* __restrict__ ur,int* __restrict__ uc,
    const float* __restrict__ hp,const float* __restrict__ ap,
    float2* __restrict__ t0,float2* __restrict__ b0,float2* __restrict__ t1,float2* __restrict__ b1,int n){
  __shared__ int sh[1024];
  int t=threadIdx.x,ch=(n+1023)>>10;
  for(int a=0;a<2;++a){
    const int* cnt=a?cc:cr; int* st=a?sc:sr; int* cu=a?uc:ur;
    int b=t*ch,hi=min(b+ch,n),s=0;
    for(int i=b;i<hi;++i)s+=cnt[i];
    sh[t]=s;__syncthreads();
    for(int o=1;o<1024;o<<=1){int v=(t>=o)?sh[t-o]:0;__syncthreads();sh[t]+=v;__syncthreads();}
    int run=(t==0)?0:sh[t-1];
    for(int i=b;i<hi;++i){st[i]=run;cu[i]=run;run+=cnt[i];}
    if(t==1023)st[n]=sh[1023];
    __syncthreads();
  }
  for(int L=0;L<2;++L){
    float h=hp[L],al=ap[L];
    float2* tl=L?t1:t0; float2* bd=L?b1:b0;
    for(int v=t;v<n;v+=1024){
      float a=h*((float)cr[v]-al),iv=1.f/(a*a+1.f),tr=a*iv,ti=-iv;
      tl[v]=make_float2(h*tr,h*ti);
      bd[v]=make_float2(tr*a+ti,ti*a-tr);
    }
  }
}

__global__ __launch_bounds__(256) void k_fill(const int* __restrict__ r,const int* __restrict__ c,
    int* __restrict__ ur,int* __restrict__ uc,int* __restrict__ ir,int* __restrict__ ic,int e){
  int i=blockIdx.x*256+threadIdx.x;
  if(i<e){
    int a=r[i],b=c[i];
    ir[atomicAdd(&ur[a],1)]=b;
    ic[atomicAdd(&uc[b],1)]=a;
  }
}

__global__ __launch_bounds__(256) void k_gemm(const float* __restrict__ X,const float* __restrict__ W,
    const float* __restrict__ Oi,float* __restrict__ Oo,int n,int cin,int acm,int cs,int rl){
  __shared__ __align__(16) float xT[8][64];
  __shared__ __align__(16) float wT[8][128];
  int tid=threadIdx.x,cg=tid&15,rg=tid>>4,r0=rg*4,rb=blockIdx.x*64;
  float2 ac[4][4];
#pragma unroll
  for(int i=0;i<4;++i)
#pragma unroll
    for(int j=0;j<4;++j)ac[i][j]=make_float2(0.f,0.f);
  int lr=tid>>1,lh=tid&1,wo=tid&127,wk=(tid>>7)*4;
  for(int k0=0;k0<cin;k0+=8){
    float4 xv=make_float4(0.f,0.f,0.f,0.f);
    if(tid<128){int gr=rb+lr;if(gr<n)xv=*(const float4*)&X[(size_t)gr*cin+k0+lh*4];}
    float4 wv=*(const float4*)&W[(size_t)wo*cin+k0+wk];
    if(cs){wv.x*=2.f;wv.y*=-2.f;wv.z*=2.f;wv.w*=-2.f;}
    __syncthreads();
    if(tid<128){
      xT[lh*4+0][lr]=xv.x;xT[lh*4+1][lr]=xv.y;xT[lh*4+2][lr]=xv.z;xT[lh*4+3][lr]=xv.w;
    }
    wT[wk+0][wo]=wv.x;wT[wk+1][wo]=wv.y;wT[wk+2][wo]=wv.z;wT[wk+3][wo]=wv.w;
    __syncthreads();
#pragma unroll
    for(int k=0;k<8;++k){
      float4 xr=*(const float4*)&xT[k][r0];
      float xa[4]={xr.x,xr.y,xr.z,xr.w};
#pragma unroll
      for(int j=0;j<4;++j){
        float2 w2=*(const float2*)&wT[k][2*cg+32*j];
#pragma unroll
        for(int i=0;i<4;++i){ac[i][j].x+=xa[i]*w2.x;ac[i][j].y+=xa[i]*w2.y;}
      }
    }
  }
#pragma unroll
  for(int i=0;i<4;++i){
    int r=rb+r0+i;
    if(r<n){
#pragma unroll
      for(int j=0;j<4;++j){
        int cf=2*cg+32*j;
        float2 rv=ac[i][j];
        if(acm){float2 o=*(const float2*)&Oi[(size_t)r*128+cf];rv.x+=o.x;rv.y+=o.y;}
        if(rl){rv.x=fmaxf(rv.x,0.f);rv.y=fmaxf(rv.y,0.f);}
        *(float2*)&Oo[(size_t)r*128+cf]=rv;
      }
    }
  }
}

__global__ __launch_bounds__(256) void k_bj(const float* __restrict__ X,const float4* __restrict__ Y,
    int cx,const int* __restrict__ st,const int* __restrict__ ix,
    const float2* __restrict__ tl,const float2* __restrict__ bd,float4* __restrict__ out,int n){
  int nd=blockIdx.x*4+(threadIdx.x>>6);
  if(nd>=n)return;
  int la=threadIdx.x&63,s=st[nd],e=st[nd+1];
  const float2* X2=(const float2*)X;
  float4 ac=make_float4(0.f,0.f,0.f,0.f),ys;
  if(cx){
    for(int i=s;i<e;++i){
      float4 yv=Y[(size_t)ix[i]*64+la];
      ac.x+=yv.x;ac.y+=yv.y;ac.z+=yv.z;ac.w+=yv.w;
    }
    ys=Y[(size_t)nd*64+la];
  }else{
    for(int i=s;i<e;++i){
      float2 xv=X2[(size_t)ix[i]*64+la];
      ac.x+=xv.x;ac.z+=xv.y;
    }
    float2 xs=X2[(size_t)nd*64+la];
    ys=make_float4(xs.x,0.f,xs.y,0.f);
  }
  float2 w=tl[nd];w.x=-w.x;w.y=-w.y;
  float2 b=bd[nd];
  float4 r;
  r.x=w.x*ac.x-w.y*ac.y+b.x*ys.x-b.y*ys.y;
  r.y=w.x*ac.y+w.y*ac.x+b.x*ys.y+b.y*ys.x;
  r.z=w.x*ac.z-w.y*ac.w+b.x*ys.z-b.y*ys.w;
  r.w=w.x*ac.w+w.y*ac.z+b.x*ys.w+b.y*ys.z;
  out[(size_t)nd*64+la]=r;
}

__global__ __launch_bounds__(256) void k_jacobi(const float4* __restrict__ Y,const float4* __restrict__ B,
    const int* __restrict__ st,const int* __restrict__ ix,const float2* __restrict__ tl,
    float4* __restrict__ out,int n){
  int nd=blockIdx.x*4+(threadIdx.x>>6);
  if(nd>=n)return;
  int la=threadIdx.x&63,s=st[nd],e=st[nd+1];
  float4 ac=make_float4(0.f,0.f,0.f,0.f);
  for(int i=s;i<e;++i){
    int u=ix[i];
    float2 t=tl[u];
    float4 yv=Y[(size_t)u*64+la];
    ac.x+=t.x*yv.x-t.y*yv.y;
    ac.y+=t.x*yv.y+t.y*yv.x;
    ac.z+=t.x*yv.z-t.y*yv.w;
    ac.w+=t.x*yv.w+t.y*yv.z;
  }
  float4 b=B[(size_t)nd*64+la];
  ac.x+=b.x;ac.y+=b.y;ac.z+=b.z;ac.w+=b.w;
  out[(size_t)nd*64+la]=ac;
}

// score = tanh((x2 . pw)/||pw||) -- store the TANH'D value (reference ranks this)
__global__ __launch_bounds__(256) void k_score(const float* __restrict__ X,const float* __restrict__ pw,
    float* __restrict__ p,int n){
  int nd=blockIdx.x*4+(threadIdx.x>>6);
  if(nd>=n)return;
  int la=threadIdx.x&63;
  float2 x=((const float2*)X)[(size_t)nd*64+la];
  float2 w=((const float2*)pw)[la];
  float s=x.x*w.x+x.y*w.y,q=w.x*w.x+w.y*w.y;
  for(int o=32;o>=1;o>>=1){s+=__shfl_down(s,o);q+=__shfl_down(q,o);}
  if(la==0)p[nd]=tanhf(s/sqrtf(q));
}

__device__ __forceinline__ unsigned f2k(float f){
  unsigned b=__float_as_uint(f);
  return b^((b>>31)?0xFFFFFFFFu:0x80000000u);
}

// exact stable top-k on tanh'd score: rank(v)=#{u: key_u>key_v or (==, u<v)}; matches lax.top_k
__global__ __launch_bounds__(256) void k_rank(const float* __restrict__ p,int n,int kp,
    float* __restrict__ ws){
  int v=blockIdx.x*256+threadIdx.x;
  if(v>=n)return;
  float tv=p[v];
  unsigned kv=f2k(tv);
  int rk=0;
  for(int u=0;u<n;++u){
    unsigned ku=f2k(p[u]);
    rk+=((ku>kv)||(ku==kv&&u<v))?1:0;
  }
  ws[v]=(rk<kp)?tv:0.f;
}

__global__ __launch_bounds__(128) void k_pool(const float* __restrict__ x2,const float* __restrict__ ws,
    float* __restrict__ po,int n){
  int c=threadIdx.x;
  float ac=0.f;
  for(int v=blockIdx.x;v<n;v+=gridDim.x){
    float w=ws[v];
    if(w!=0.f)ac+=w*x2[(size_t)v*128+c];
  }
  atomicAdd(&po[c],ac);
}

__global__ void k_final(const float* __restrict__ po,const float* __restrict__ lw,
    const float* __restrict__ lb,float* __restrict__ out,int kp){
  int t=threadIdx.x;
  if(t<10){
    float s=0.f;
    for(int c=0;c<128;++c)s+=po[c]*lw[t*128+c];
    out[t]=s/(float)kp+lb[t];
  }
}

extern "C" void kernel_launch(void* const* d_in,const int* in_sizes,int n_in,
                              void* d_out,int out_size,void* d_ws,size_t ws_size,hipStream_t stream){
  const float* x=(const float*)d_in[0];
  const int* ei=(const int*)d_in[1];
  const float* Wr1=(const float*)d_in[2];
  const float* Wc1=(const float*)d_in[3];
  const float* Wr2=(const float*)d_in[4];
  const float* Wc2=(const float*)d_in[5];
  const float* hp=(const float*)d_in[6];
  const float* ap=(const float*)d_in[7];
  const float* pw=(const float*)d_in[8];
  const float* lW=(const float*)d_in[9];
  const float* lb=(const float*)d_in[10];
  int n=in_sizes[0]/128,e=in_sizes[1]/2;
  const int* row=ei;
  const int* col=ei+e;
  int kp=(int)ceil(0.9*(double)n);
  char* wb=(char*)d_ws;
  size_t off=0;
  auto al=[&](size_t b)->void*{off=(off+255)&~(size_t)255;void* p=wb+off;off+=b;return p;};
  int* cnt=(int*)al(sizeof(int)*2*n);
  int* cr=cnt;int* cc=cnt+n;
  int* sr=(int*)al(sizeof(int)*(n+1));
  int* sc=(int*)al(sizeof(int)*(n+1));
  int* ur=(int*)al(sizeof(int)*n);
  int* uc=(int*)al(sizeof(int)*n);
  int* ir=(int*)al(sizeof(int)*e);
  int* ic=(int*)al(sizeof(int)*e);
  float2* t0=(float2*)al(sizeof(float2)*n);
  float2* b0=(float2*)al(sizeof(float2)*n);
  float2* t1=(float2*)al(sizeof(float2)*n);
  float2* b1=(float2*)al(sizeof(float2)*n);
  float* pb=(float*)al(sizeof(float)*n);
  float* ws=(float*)al(sizeof(float)*n);
  float* po=(float*)al(sizeof(float)*128);
  float* yb=(float*)al(sizeof(float)*(size_t)n*256);
  float* bj=(float*)al(sizeof(float)*(size_t)n*256);
  float* tb=(float*)al(sizeof(float)*(size_t)n*256);
  float* xa=(float*)al(sizeof(float)*(size_t)n*128);
  float* oa=(float*)al(sizeof(float)*(size_t)n*128);
  (void)n_in;(void)out_size;
  if(off>ws_size)return;
  int gE=(e+255)/256,gN=(n+255)/256,g4=(n+3)/4,gG=(n+63)/64;
  (void)hipMemsetAsync(cnt,0,sizeof(int)*2*n,stream);
  k_count<<<gE,256,0,stream>>>(row,col,cr,cc,e);
  k_scan<<<1,1024,0,stream>>>(cr,cc,sr,sc,ur,uc,hp,ap,t0,b0,t1,b1,n);
  k_fill<<<gE,256,0,stream>>>(row,col,ur,uc,ir,ic,e);
  for(int L=0;L<2;++L){
    const float* xi=L?xa:x;
    const float* Wr=L?Wr2:Wr1;
    const float* Wc=L?Wc2:Wc1;
    float* ro=L?oa:xa;
    const float2* tl=L?t1:t0;
    const float2* bd=L?b1:b0;
    k_gemm<<<gG,256,0,stream>>>(xi,Wr,oa,oa,n,128,0,0,0);
    k_bj<<<g4,256,0,stream>>>(xi,(const float4*)xi,0,sr,ir,tl,bd,(float4*)bj,n);
    k_jacobi<<<g4,256,0,stream>>>((float4*)bj,(float4*)bj,sc,ic,tl,(float4*)tb,n);
    k_jacobi<<<g4,256,0,stream>>>((float4*)tb,(float4*)bj,sc,ic,tl,(float4*)yb,n);
    k_jacobi<<<g4,256,0,stream>>>((float4*)yb,(float4*)bj,sc,ic,tl,(float4*)tb,n);
    k_gemm<<<gG,256,0,stream>>>(tb,Wc,oa,oa,n,256,1,1,0);
    k_bj<<<g4,256,0,stream>>>(tb,(const float4*)tb,1,sr,ir,tl,bd,(float4*)bj,n);
    k_jacobi<<<g4,256,0,stream>>>((float4*)bj,(float4*)bj,sc,ic,tl,(float4*)yb,n);
    k_jacobi<<<g4,256,0,stream>>>((float4*)yb,(float4*)bj,sc,ic,tl,(float4*)tb,n);
    k_jacobi<<<g4,256,0,stream>>>((float4*)tb,(float4*)bj,sc,ic,tl,(float4*)yb,n);
    k_gemm<<<gG,256,0,stream>>>(yb,Wc+(size_t)128*256,oa,ro,n,256,1,1,1);
  }
  k_score<<<g4,256,0,stream>>>(oa,pw,pb,n);
  k_rank<<<gN,256,0,stream>>>(pb,n,kp,ws);
  (void)hipMemsetAsync(po,0,sizeof(float)*128,stream);
  k_pool<<<512,128,0,stream>>>(oa,ws,po,n);
  k_final<<<1,64,0,stream>>>(po,lW,lb,(float*)d_out,kp);
}

// Round 46
// 1741.228 us; speedup vs baseline: 1.2803x; 1.2803x over previous
//
#include <hip/hip_runtime.h>
#include <cstdint>
#include <cmath>

__global__ __launch_bounds__(256) void k_count(const int* __restrict__ r,const int* __restrict__ c,
    int* __restrict__ cr,int* __restrict__ cc,int e){
  int i=blockIdx.x*256+threadIdx.x;
  if(i<e){atomicAdd(&cr[r[i]],1);atomicAdd(&cc[c[i]],1);}
}

__global__ __launch_bounds__(1024) void k_scan(const int* __restrict__ cr,const int* __restrict__ cc,
    int* __restrict__ sr,int* __restrict__ sc,int* __restrict__ ur,int* __restrict__ uc,
    const float* __restrict__ hp,const float* __restrict__ ap,
    float2* __restrict__ t0,float2* __restrict__ b0,float2* __restrict__ t1,float2* __restrict__ b1,int n){
  __shared__ int sh[1024];
  int t=threadIdx.x,ch=(n+1023)>>10;
  for(int a=0;a<2;++a){
    const int* cnt=a?cc:cr; int* st=a?sc:sr; int* cu=a?uc:ur;
    int b=t*ch,hi=min(b+ch,n),s=0;
    for(int i=b;i<hi;++i)s+=cnt[i];
    sh[t]=s;__syncthreads();
    for(int o=1;o<1024;o<<=1){int v=(t>=o)?sh[t-o]:0;__syncthreads();sh[t]+=v;__syncthreads();}
    int run=(t==0)?0:sh[t-1];
    for(int i=b;i<hi;++i){st[i]=run;cu[i]=run;run+=cnt[i];}
    if(t==1023)st[n]=sh[1023];
    __syncthreads();
  }
  for(int L=0;L<2;++L){
    float h=hp[L],al=ap[L];
    float2* tl=L?t1:t0; float2* bd=L?b1:b0;
    for(int v=t;v<n;v+=1024){
      float a=h*((float)cr[v]-al),iv=1.f/(a*a+1.f),tr=a*iv,ti=-iv;
      tl[v]=make_float2(h*tr,h*ti);
      bd[v]=make_float2(tr*a+ti,ti*a-tr);
    }
  }
}

__global__ __launch_bounds__(256) void k_fill(const int* __restrict__ r,const int* __restrict__ c,
    int* __restrict__ ur,int* __restrict__ uc,int* __restrict__ ir,int* __restrict__ ic,int e){
  int i=blockIdx.x*256+threadIdx.x;
  if(i<e){
    int a=r[i],b=c[i];
    ir[atomicAdd(&ur[a],1)]=b;
    ic[atomicAdd(&uc[b],1)]=a;
  }
}

__global__ __launch_bounds__(256) void k_gemm(const float* __restrict__ X,const float* __restrict__ W,
    const float* __restrict__ Oi,float* __restrict__ Oo,int n,int cin,int acm,int cs,int rl){
  __shared__ __align__(16) float xT[8][64];
  __shared__ __align__(16) float wT[8][128];
  int tid=threadIdx.x,cg=tid&15,rg=tid>>4,r0=rg*4,rb=blockIdx.x*64;
  float2 ac[4][4];
#pragma unroll
  for(int i=0;i<4;++i)
#pragma unroll
    for(int j=0;j<4;++j)ac[i][j]=make_float2(0.f,0.f);
  int lr=tid>>1,lh=tid&1,wo=tid&127,wk=(tid>>7)*4;
  for(int k0=0;k0<cin;k0+=8){
    float4 xv=make_float4(0.f,0.f,0.f,0.f);
    if(tid<128){int gr=rb+lr;if(gr<n)xv=*(const float4*)&X[(size_t)gr*cin+k0+lh*4];}
    float4 wv=*(const float4*)&W[(size_t)wo*cin+k0+wk];
    if(cs){wv.x*=2.f;wv.y*=-2.f;wv.z*=2.f;wv.w*=-2.f;}
    __syncthreads();
    if(tid<128){
      xT[lh*4+0][lr]=xv.x;xT[lh*4+1][lr]=xv.y;xT[lh*4+2][lr]=xv.z;xT[lh*4+3][lr]=xv.w;
    }
    wT[wk+0][wo]=wv.x;wT[wk+1][wo]=wv.y;wT[wk+2][wo]=wv.z;wT[wk+3][wo]=wv.w;
    __syncthreads();
#pragma unroll
    for(int k=0;k<8;++k){
      float4 xr=*(const float4*)&xT[k][r0];
      float xa[4]={xr.x,xr.y,xr.z,xr.w};
#pragma unroll
      for(int j=0;j<4;++j){
        float2 w2=*(const float2*)&wT[k][2*cg+32*j];
#pragma unroll
        for(int i=0;i<4;++i){ac[i][j].x+=xa[i]*w2.x;ac[i][j].y+=xa[i]*w2.y;}
      }
    }
  }
#pragma unroll
  for(int i=0;i<4;++i){
    int r=rb+r0+i;
    if(r<n){
#pragma unroll
      for(int j=0;j<4;++j){
        int cf=2*cg+32*j;
        float2 rv=ac[i][j];
        if(acm){float2 o=*(const float2*)&Oi[(size_t)r*128+cf];rv.x+=o.x;rv.y+=o.y;}
        if(rl){rv.x=fmaxf(rv.x,0.f);rv.y=fmaxf(rv.y,0.f);}
        *(float2*)&Oo[(size_t)r*128+cf]=rv;
      }
    }
  }
}

__global__ __launch_bounds__(256) void k_bj(const float* __restrict__ X,const float4* __restrict__ Y,
    int cx,const int* __restrict__ st,const int* __restrict__ ix,
    const float2* __restrict__ tl,const float2* __restrict__ bd,float4* __restrict__ out,int n){
  int nd=blockIdx.x*4+(threadIdx.x>>6);
  if(nd>=n)return;
  int la=threadIdx.x&63,s=st[nd],e=st[nd+1];
  const float2* X2=(const float2*)X;
  float4 ac=make_float4(0.f,0.f,0.f,0.f),ys;
  if(cx){
    for(int i=s;i<e;++i){
      float4 yv=Y[(size_t)ix[i]*64+la];
      ac.x+=yv.x;ac.y+=yv.y;ac.z+=yv.z;ac.w+=yv.w;
    }
    ys=Y[(size_t)nd*64+la];
  }else{
    for(int i=s;i<e;++i){
      float2 xv=X2[(size_t)ix[i]*64+la];
      ac.x+=xv.x;ac.z+=xv.y;
    }
    float2 xs=X2[(size_t)nd*64+la];
    ys=make_float4(xs.x,0.f,xs.y,0.f);
  }
  float2 w=tl[nd];w.x=-w.x;w.y=-w.y;
  float2 b=bd[nd];
  float4 r;
  r.x=w.x*ac.x-w.y*ac.y+b.x*ys.x-b.y*ys.y;
  r.y=w.x*ac.y+w.y*ac.x+b.x*ys.y+b.y*ys.x;
  r.z=w.x*ac.z-w.y*ac.w+b.x*ys.z-b.y*ys.w;
  r.w=w.x*ac.w+w.y*ac.z+b.x*ys.w+b.y*ys.z;
  out[(size_t)nd*64+la]=r;
}

__global__ __launch_bounds__(256) void k_jacobi(const float4* __restrict__ Y,const float4* __restrict__ B,
    const int* __restrict__ st,const int* __restrict__ ix,const float2* __restrict__ tl,
    float4* __restrict__ out,int n){
  int nd=blockIdx.x*4+(threadIdx.x>>6);
  if(nd>=n)return;
  int la=threadIdx.x&63,s=st[nd],e=st[nd+1];
  float4 ac=make_float4(0.f,0.f,0.f,0.f);
  for(int i=s;i<e;++i){
    int u=ix[i];
    float2 t=tl[u];
    float4 yv=Y[(size_t)u*64+la];
    ac.x+=t.x*yv.x-t.y*yv.y;
    ac.y+=t.x*yv.y+t.y*yv.x;
    ac.z+=t.x*yv.z-t.y*yv.w;
    ac.w+=t.x*yv.w+t.y*yv.z;
  }
  float4 b=B[(size_t)nd*64+la];
  ac.x+=b.x;ac.y+=b.y;ac.z+=b.z;ac.w+=b.w;
  out[(size_t)nd*64+la]=ac;
}

// score = tanh((x2 . pw)/||pw||) -- store the TANH'D value (reference ranks this)
__global__ __launch_bounds__(256) void k_score(const float* __restrict__ X,const float* __restrict__ pw,
    float* __restrict__ p,int n){
  int nd=blockIdx.x*4+(threadIdx.x>>6);
  if(nd>=n)return;
  int la=threadIdx.x&63;
  float2 x=((const float2*)X)[(size_t)nd*64+la];
  float2 w=((const float2*)pw)[la];
  float s=x.x*w.x+x.y*w.y,q=w.x*w.x+w.y*w.y;
  for(int o=32;o>=1;o>>=1){s+=__shfl_down(s,o);q+=__shfl_down(q,o);}
  if(la==0)p[nd]=tanhf(s/sqrtf(q));
}

__device__ __forceinline__ unsigned f2k(float f){
  unsigned b=__float_as_uint(f);
  return b^((b>>31)?0xFFFFFFFFu:0x80000000u);
}

// exact stable top-k on tanh'd score, LDS-tiled scan: rank(v)=#{u: key_u>key_v or (==, u<v)}
__global__ __launch_bounds__(256) void k_rank(const float* __restrict__ p,int n,int kp,
    float* __restrict__ ws){
  __shared__ unsigned sk[2048];
  int v=blockIdx.x*256+threadIdx.x;
  float tv=(v<n)?p[v]:0.f;
  unsigned kv=f2k(tv);
  int rk=0;
  for(int base=0;base<n;base+=2048){
    int m=min(2048,n-base);
    __syncthreads();
    for(int i=threadIdx.x;i<m;i+=256) sk[i]=f2k(p[base+i]);
    __syncthreads();
    if(v<n){
      for(int i=0;i<m;++i){
        unsigned ku=sk[i];
        int u=base+i;
        rk+=((ku>kv)||(ku==kv&&u<v))?1:0;
      }
    }
  }
  if(v<n) ws[v]=(rk<kp)?tv:0.f;
}

__global__ __launch_bounds__(128) void k_pool(const float* __restrict__ x2,const float* __restrict__ ws,
    float* __restrict__ po,int n){
  int c=threadIdx.x;
  float ac=0.f;
  for(int v=blockIdx.x;v<n;v+=gridDim.x){
    float w=ws[v];
    if(w!=0.f)ac+=w*x2[(size_t)v*128+c];
  }
  atomicAdd(&po[c],ac);
}

__global__ void k_final(const float* __restrict__ po,const float* __restrict__ lw,
    const float* __restrict__ lb,float* __restrict__ out,int kp){
  int t=threadIdx.x;
  if(t<10){
    float s=0.f;
    for(int c=0;c<128;++c)s+=po[c]*lw[t*128+c];
    out[t]=s/(float)kp+lb[t];
  }
}

extern "C" void kernel_launch(void* const* d_in,const int* in_sizes,int n_in,
                              void* d_out,int out_size,void* d_ws,size_t ws_size,hipStream_t stream){
  const float* x=(const float*)d_in[0];
  const int* ei=(const int*)d_in[1];
  const float* Wr1=(const float*)d_in[2];
  const float* Wc1=(const float*)d_in[3];
  const float* Wr2=(const float*)d_in[4];
  const float* Wc2=(const float*)d_in[5];
  const float* hp=(const float*)d_in[6];
  const float* ap=(const float*)d_in[7];
  const float* pw=(const float*)d_in[8];
  const float* lW=(const float*)d_in[9];
  const float* lb=(const float*)d_in[10];
  int n=in_sizes[0]/128,e=in_sizes[1]/2;
  const int* row=ei;
  const int* col=ei+e;
  int kp=(int)ceil(0.9*(double)n);
  char* wb=(char*)d_ws;
  size_t off=0;
  auto al=[&](size_t b)->void*{off=(off+255)&~(size_t)255;void* p=wb+off;off+=b;return p;};
  int* cnt=(int*)al(sizeof(int)*2*n);
  int* cr=cnt;int* cc=cnt+n;
  int* sr=(int*)al(sizeof(int)*(n+1));
  int* sc=(int*)al(sizeof(int)*(n+1));
  int* ur=(int*)al(sizeof(int)*n);
  int* uc=(int*)al(sizeof(int)*n);
  int* ir=(int*)al(sizeof(int)*e);
  int* ic=(int*)al(sizeof(int)*e);
  float2* t0=(float2*)al(sizeof(float2)*n);
  float2* b0=(float2*)al(sizeof(float2)*n);
  float2* t1=(float2*)al(sizeof(float2)*n);
  float2* b1=(float2*)al(sizeof(float2)*n);
  float* pb=(float*)al(sizeof(float)*n);
  float* ws=(float*)al(sizeof(float)*n);
  float* po=(float*)al(sizeof(float)*128);
  float* yb=(float*)al(sizeof(float)*(size_t)n*256);
  float* bj=(float*)al(sizeof(float)*(size_t)n*256);
  float* tb=(float*)al(sizeof(float)*(size_t)n*256);
  float* xa=(float*)al(sizeof(float)*(size_t)n*128);
  float* oa=(float*)al(sizeof(float)*(size_t)n*128);
  (void)n_in;(void)out_size;
  if(off>ws_size)return;
  int gE=(e+255)/256,gN=(n+255)/256,g4=(n+3)/4,gG=(n+63)/64;
  (void)hipMemsetAsync(cnt,0,sizeof(int)*2*n,stream);
  k_count<<<gE,256,0,stream>>>(row,col,cr,cc,e);
  k_scan<<<1,1024,0,stream>>>(cr,cc,sr,sc,ur,uc,hp,ap,t0,b0,t1,b1,n);
  k_fill<<<gE,256,0,stream>>>(row,col,ur,uc,ir,ic,e);
  for(int L=0;L<2;++L){
    const float* xi=L?xa:x;
    const float* Wr=L?Wr2:Wr1;
    const float* Wc=L?Wc2:Wc1;
    float* ro=L?oa:xa;
    const float2* tl=L?t1:t0;
    const float2* bd=L?b1:b0;
    k_gemm<<<gG,256,0,stream>>>(xi,Wr,oa,oa,n,128,0,0,0);
    k_bj<<<g4,256,0,stream>>>(xi,(const float4*)xi,0,sr,ir,tl,bd,(float4*)bj,n);
    k_jacobi<<<g4,256,0,stream>>>((float4*)bj,(float4*)bj,sc,ic,tl,(float4*)tb,n);
    k_jacobi<<<g4,256,0,stream>>>((float4*)tb,(float4*)bj,sc,ic,tl,(float4*)yb,n);
    k_jacobi<<<g4,256,0,stream>>>((float4*)yb,(float4*)bj,sc,ic,tl,(float4*)tb,n);
    k_gemm<<<gG,256,0,stream>>>(tb,Wc,oa,oa,n,256,1,1,0);
    k_bj<<<g4,256,0,stream>>>(tb,(const float4*)tb,1,sr,ir,tl,bd,(float4*)bj,n);
    k_jacobi<<<g4,256,0,stream>>>((float4*)bj,(float4*)bj,sc,ic,tl,(float4*)yb,n);
    k_jacobi<<<g4,256,0,stream>>>((float4*)yb,(float4*)bj,sc,ic,tl,(float4*)tb,n);
    k_jacobi<<<g4,256,0,stream>>>((float4*)tb,(float4*)bj,sc,ic,tl,(float4*)yb,n);
    k_gemm<<<gG,256,0,stream>>>(yb,Wc+(size_t)128*256,oa,ro,n,256,1,1,1);
  }
  k_score<<<g4,256,0,stream>>>(oa,pw,pb,n);
  k_rank<<<gN,256,0,stream>>>(pb,n,kp,ws);
  (void)hipMemsetAsync(po,0,sizeof(float)*128,stream);
  k_pool<<<512,128,0,stream>>>(oa,ws,po,n);
  k_final<<<1,64,0,stream>>>(po,lW,lb,(float*)d_out,kp);
}